// Round 1
// baseline (373.125 us; speedup 1.0000x reference)
//
#include <hip/hip_runtime.h>
#include <cstdint>
#include <cmath>

#define NN 100000      // nodes
#define NC 8           // communities
#define NF 256         // features (and D)
// x_parts region in d_out: NC*NN*NF floats, then mask tail NN*NC floats
#define XPARTS_FLOATS ((size_t)NC * NN * NF)   // 204,800,000

// ---------------- K1: phi_raw[n][c] = mean(z[n, c*32:(c+1)*32]) in fp64 -----
__global__ void k_phi_raw(const float* __restrict__ z, double* __restrict__ raw) {
    int gid = blockIdx.x * blockDim.x + threadIdx.x;
    if (gid >= NN * NC) return;
    int n = gid >> 3, c = gid & 7;
    const float4* zp = reinterpret_cast<const float4*>(z) + (size_t)n * 64 + c * 8;
    double s = 0.0;
#pragma unroll
    for (int i = 0; i < 8; ++i) {
        float4 v = zp[i];
        s += ((double)v.x + (double)v.y) + ((double)v.z + (double)v.w);
    }
    raw[gid] = s * (1.0 / 32.0);
}

// online softmax merge: (m,s) <- (m,s) ⊕ (m2,s2)
__device__ inline void ms_merge(double& m, double& s, double m2, double s2) {
    if (m2 > m) { s = s * exp(m - m2) + s2; m = m2; }
    else        { s = s + s2 * exp(m2 - m); }
}

// ---------------- K2: per-block column (max, sum-exp) partials --------------
__global__ void k_col_partial(const double* __restrict__ raw, double* __restrict__ part) {
    __shared__ double sm[256][NC];
    __shared__ double ss[256][NC];
    int tid = threadIdx.x;
    int gtid = blockIdx.x * 256 + tid;
    double m[NC], s[NC];
#pragma unroll
    for (int c = 0; c < NC; ++c) { m[c] = -1e300; s[c] = 0.0; }
    for (int n = gtid; n < NN; n += 256 * 256) {
        const double* rp = raw + (size_t)n * NC;
#pragma unroll
        for (int c = 0; c < NC; ++c) ms_merge(m[c], s[c], rp[c], 1.0);
    }
#pragma unroll
    for (int c = 0; c < NC; ++c) { sm[tid][c] = m[c]; ss[tid][c] = s[c]; }
    __syncthreads();
    for (int off = 128; off > 0; off >>= 1) {
        if (tid < off) {
#pragma unroll
            for (int c = 0; c < NC; ++c) {
                double mm = sm[tid][c], sc = ss[tid][c];
                ms_merge(mm, sc, sm[tid + off][c], ss[tid + off][c]);
                sm[tid][c] = mm; ss[tid][c] = sc;
            }
        }
        __syncthreads();
    }
    if (tid == 0) {
#pragma unroll
        for (int c = 0; c < NC; ++c) {
            part[(size_t)blockIdx.x * 16 + 2 * c]     = sm[0][c];
            part[(size_t)blockIdx.x * 16 + 2 * c + 1] = ss[0][c];
        }
    }
}

// ---------------- K3: merge 256 block partials -> final (M_c, S_c) ---------
__global__ void k_col_final(const double* __restrict__ part, double* __restrict__ fin) {
    __shared__ double sm[256][NC];
    __shared__ double ss[256][NC];
    int tid = threadIdx.x;
#pragma unroll
    for (int c = 0; c < NC; ++c) {
        sm[tid][c] = part[(size_t)tid * 16 + 2 * c];
        ss[tid][c] = part[(size_t)tid * 16 + 2 * c + 1];
    }
    __syncthreads();
    for (int off = 128; off > 0; off >>= 1) {
        if (tid < off) {
#pragma unroll
            for (int c = 0; c < NC; ++c) {
                double mm = sm[tid][c], sc = ss[tid][c];
                ms_merge(mm, sc, sm[tid + off][c], ss[tid + off][c]);
                sm[tid][c] = mm; ss[tid][c] = sc;
            }
        }
        __syncthreads();
    }
    if (tid == 0) {
#pragma unroll
        for (int c = 0; c < NC; ++c) {
            fin[2 * c]     = sm[0][c];
            fin[2 * c + 1] = ss[0][c];
        }
    }
}

// ---------------- K4: per-node mask (fp64), write 0/1 floats to tail -------
__global__ void k_mask(const double* __restrict__ raw, const double* __restrict__ fin,
                       float* __restrict__ mask_out) {
    int n = blockIdx.x * blockDim.x + threadIdx.x;
    if (n >= NN) return;
    double phi[NC];
    double r = 0.0;
#pragma unroll
    for (int c = 0; c < NC; ++c) {
        phi[c] = exp(raw[(size_t)n * NC + c] - fin[2 * c]) / fin[2 * c + 1];
        r += phi[c];
    }
    // r.sum() over all nodes == 8 (each column softmax sums to 1); fp64-exact
    double f = 8.0 - r;
    double w[NC];
    double wmax = -1e300;
#pragma unroll
    for (int c = 0; c < NC; ++c) { w[c] = phi[c] * f; wmax = fmax(wmax, w[c]); }
#pragma unroll
    for (int c = 0; c < NC; ++c) {
        bool bit = (w[c] == wmax) || (w[c] >= 1.0);
        mask_out[(size_t)n * NC + c] = bit ? 1.0f : 0.0f;
    }
}

// ---------------- K5: scatter x into x_parts (write-BW bound) --------------
__global__ void k_scatter(const float* __restrict__ x, const float* __restrict__ mask,
                          float4* __restrict__ out4) {
    int tid = threadIdx.x;
    int n = blockIdx.x * 4 + (tid >> 6);       // 4 rows per 256-thread block
    int lane = tid & 63;
    const float4* x4 = reinterpret_cast<const float4*>(x);
    float4 v = x4[(size_t)n * 64 + lane];
    const float4 zz = make_float4(0.f, 0.f, 0.f, 0.f);
#pragma unroll
    for (int c = 0; c < NC; ++c) {
        bool bit = mask[(size_t)n * NC + c] != 0.0f;
        out4[(size_t)c * NN * 64 + (size_t)n * 64 + lane] = bit ? v : zz;
    }
}

extern "C" void kernel_launch(void* const* d_in, const int* in_sizes, int n_in,
                              void* d_out, int out_size, void* d_ws, size_t ws_size,
                              hipStream_t stream) {
    const float* x = (const float*)d_in[0];
    const float* z = (const float*)d_in[1];
    float* out = (float*)d_out;

    // scratch carved from the x_parts region of d_out (overwritten by K5 later)
    double* raw  = (double*)out;                       // 800,000 doubles = floats [0, 1.6M)
    double* part = (double*)(out + 2000000);           // 4096 doubles (byte off 8e6, aligned)
    double* fin  = (double*)(out + 2200000);           // 16 doubles  (byte off 8.8e6, aligned)
    float* mask_out = out + XPARTS_FLOATS;             // final mask location (tail)

    k_phi_raw   <<<(NN * NC + 255) / 256, 256, 0, stream>>>(z, raw);
    k_col_partial<<<256, 256, 0, stream>>>(raw, part);
    k_col_final <<<1, 256, 0, stream>>>(part, fin);
    k_mask      <<<(NN + 255) / 256, 256, 0, stream>>>(raw, fin, mask_out);
    k_scatter   <<<NN / 4, 256, 0, stream>>>(x, mask_out, (float4*)out);
}

// Round 3
// 201.855 us; speedup vs baseline: 1.8485x; 1.8485x over previous
//
#include <hip/hip_runtime.h>
#include <cstdint>
#include <cmath>

#define NN 100000      // nodes
#define NC 8           // communities
#define NF 256         // features (and D)
#define XPARTS_FLOATS ((size_t)NC * NN * NF)   // 204,800,000

typedef float f32x4 __attribute__((ext_vector_type(4)));   // nontemporal-store-friendly

// ---- K1: phi_raw[n][c] = mean(z[n, c*32:(c+1)*32]) in fp64, coalesced -----
// wave-per-row: lane l loads z[n][4l..4l+3]; 8-lane-group shuffle reduce.
__global__ __launch_bounds__(256) void k_phi_raw(const f32x4* __restrict__ z4,
                                                 double* __restrict__ raw) {
    int gid = blockIdx.x * 256 + threadIdx.x;
    int n = gid >> 6;
    int l = gid & 63;
    if (n >= NN) return;
    f32x4 v = z4[(size_t)n * 64 + l];
    double s = ((double)v.x + (double)v.y) + ((double)v.z + (double)v.w);
    s += __shfl_xor(s, 1, 64);
    s += __shfl_xor(s, 2, 64);
    s += __shfl_xor(s, 4, 64);
    if ((l & 7) == 0) raw[(size_t)n * NC + (l >> 3)] = s * (1.0 / 32.0);
}

// ---- K2: per-block column sum-of-exp partials (max-free, fp64) ------------
// raw = mean of 32 N(0,1) samples -> |raw| < ~0.5, exp() never overflows.
__global__ __launch_bounds__(256) void k_col_partial(const double* __restrict__ raw,
                                                     double* __restrict__ part) {
    __shared__ double ss[256][NC];
    int tid = threadIdx.x;
    int gtid = blockIdx.x * 256 + tid;
    double s[NC];
#pragma unroll
    for (int c = 0; c < NC; ++c) s[c] = 0.0;
    for (int n = gtid; n < NN; n += 256 * 256) {
        const double* rp = raw + (size_t)n * NC;
#pragma unroll
        for (int c = 0; c < NC; ++c) s[c] += exp(rp[c]);
    }
#pragma unroll
    for (int c = 0; c < NC; ++c) ss[tid][c] = s[c];
    __syncthreads();
    for (int off = 128; off > 0; off >>= 1) {
        if (tid < off) {
#pragma unroll
            for (int c = 0; c < NC; ++c) ss[tid][c] += ss[tid + off][c];
        }
        __syncthreads();
    }
    if (tid == 0) {
#pragma unroll
        for (int c = 0; c < NC; ++c) part[(size_t)blockIdx.x * NC + c] = ss[0][c];
    }
}

// ---- K3: merge 256 block partials -> final S_c ----------------------------
__global__ __launch_bounds__(256) void k_col_final(const double* __restrict__ part,
                                                   double* __restrict__ fin) {
    __shared__ double ss[256][NC];
    int tid = threadIdx.x;
#pragma unroll
    for (int c = 0; c < NC; ++c) ss[tid][c] = part[(size_t)tid * NC + c];
    __syncthreads();
    for (int off = 128; off > 0; off >>= 1) {
        if (tid < off) {
#pragma unroll
            for (int c = 0; c < NC; ++c) ss[tid][c] += ss[tid + off][c];
        }
        __syncthreads();
    }
    if (tid == 0) {
#pragma unroll
        for (int c = 0; c < NC; ++c) fin[c] = ss[0][c];
    }
}

// ---- K4: per-node mask (fp64), 0/1 floats to the output tail --------------
__global__ __launch_bounds__(256) void k_mask(const double* __restrict__ raw,
                                              const double* __restrict__ fin,
                                              float* __restrict__ mask_out) {
    int n = blockIdx.x * blockDim.x + threadIdx.x;
    if (n >= NN) return;
    double phi[NC];
    double r = 0.0;
#pragma unroll
    for (int c = 0; c < NC; ++c) {
        phi[c] = exp(raw[(size_t)n * NC + c]) / fin[c];
        r += phi[c];
    }
    double f = 8.0 - r;   // sum over all nodes of rowsum(phi) == 8 exactly
    double w[NC];
    double wmax = -1e300;
#pragma unroll
    for (int c = 0; c < NC; ++c) { w[c] = phi[c] * f; wmax = fmax(wmax, w[c]); }
#pragma unroll
    for (int c = 0; c < NC; ++c) {
        bool bit = (w[c] == wmax) || (w[c] >= 1.0);
        mask_out[(size_t)n * NC + c] = bit ? 1.0f : 0.0f;
    }
}

// ---- K5: scatter x into x_parts — 64 rows/block in registers, c-major -----
__global__ __launch_bounds__(256) void k_scatter(const f32x4* __restrict__ x4,
                                                 const float* __restrict__ mask,
                                                 f32x4* __restrict__ out4) {
    __shared__ float mlds[64 * NC];
    int tid = threadIdx.x;
    int b = blockIdx.x;
    int r0 = b * 64;
    int nrows = NN - r0; if (nrows > 64) nrows = 64;
    int nvec = nrows * 64;                   // float4 count for this block
    size_t base = (size_t)r0 * 64;           // float4 index of first row

    // stage mask for these rows in LDS
    for (int k = tid; k < nrows * NC; k += 256)
        mlds[k] = mask[(size_t)r0 * NC + k];

    // pull x rows into registers (16 float4 / thread)
    f32x4 v[16];
#pragma unroll
    for (int i = 0; i < 16; ++i) {
        int idx = i * 256 + tid;
        v[i] = (idx < nvec) ? x4[base + idx] : (f32x4)(0.f);
    }
    __syncthreads();

    const f32x4 zz = (f32x4)(0.f);
#pragma unroll
    for (int c = 0; c < NC; ++c) {
        size_t cbase = (size_t)c * NN * 64 + base;
#pragma unroll
        for (int i = 0; i < 16; ++i) {
            int idx = i * 256 + tid;
            if (idx < nvec) {
                int lr = idx >> 6;                       // wave-uniform row
                bool bit = mlds[lr * NC + c] != 0.0f;    // LDS broadcast
                __builtin_nontemporal_store(bit ? v[i] : zz, &out4[cbase + idx]);
            }
        }
    }
}

extern "C" void kernel_launch(void* const* d_in, const int* in_sizes, int n_in,
                              void* d_out, int out_size, void* d_ws, size_t ws_size,
                              hipStream_t stream) {
    const float* x = (const float*)d_in[0];
    const float* z = (const float*)d_in[1];
    float* out = (float*)d_out;

    // scratch carved from the x_parts region of d_out (fully overwritten by K5)
    double* raw  = (double*)out;               // 800,000 doubles
    double* part = (double*)(out + 2000000);   // 2048 doubles
    double* fin  = (double*)(out + 2200000);   // 8 doubles
    float* mask_out = out + XPARTS_FLOATS;     // output tail [N, C]

    k_phi_raw    <<<(NN * 64 + 255) / 256, 256, 0, stream>>>((const f32x4*)z, raw);
    k_col_partial<<<256, 256, 0, stream>>>(raw, part);
    k_col_final  <<<1, 256, 0, stream>>>(part, fin);
    k_mask       <<<(NN + 255) / 256, 256, 0, stream>>>(raw, fin, mask_out);
    k_scatter    <<<(NN + 63) / 64, 256, 0, stream>>>((const f32x4*)x, mask_out, (f32x4*)out);
}

// Round 4
// 200.175 us; speedup vs baseline: 1.8640x; 1.0084x over previous
//
#include <hip/hip_runtime.h>
#include <cstdint>
#include <cmath>

#define NN 100000      // nodes
#define NC 8           // communities
#define NF 256         // features (and D)
#define XPARTS_FLOATS ((size_t)NC * NN * NF)   // 204,800,000

typedef float f32x4 __attribute__((ext_vector_type(4)));

// ---- K1: phi_raw[n][c] = mean(z[n, c*32:(c+1)*32]) in fp64, coalesced -----
__global__ __launch_bounds__(256) void k_phi_raw(const f32x4* __restrict__ z4,
                                                 double* __restrict__ raw) {
    int gid = blockIdx.x * 256 + threadIdx.x;
    int n = gid >> 6;
    int l = gid & 63;
    if (n >= NN) return;
    f32x4 v = z4[(size_t)n * 64 + l];
    double s = ((double)v.x + (double)v.y) + ((double)v.z + (double)v.w);
    s += __shfl_xor(s, 1, 64);
    s += __shfl_xor(s, 2, 64);
    s += __shfl_xor(s, 4, 64);
    if ((l & 7) == 0) raw[(size_t)n * NC + (l >> 3)] = s * (1.0 / 32.0);
}

// ---- K2: per-block column sum-of-exp partials (max-free, fp64) ------------
// raw = mean of 32 N(0,1) -> |raw| < ~0.5, exp never overflows: no max needed.
__global__ __launch_bounds__(256) void k_col_partial(const double* __restrict__ raw,
                                                     double* __restrict__ part) {
    __shared__ double ss[256][NC];
    int tid = threadIdx.x;
    int gtid = blockIdx.x * 256 + tid;
    double s[NC];
#pragma unroll
    for (int c = 0; c < NC; ++c) s[c] = 0.0;
    for (int n = gtid; n < NN; n += 256 * 256) {
        const double* rp = raw + (size_t)n * NC;
#pragma unroll
        for (int c = 0; c < NC; ++c) s[c] += exp(rp[c]);
    }
#pragma unroll
    for (int c = 0; c < NC; ++c) ss[tid][c] = s[c];
    __syncthreads();
    for (int off = 128; off > 0; off >>= 1) {
        if (tid < off) {
#pragma unroll
            for (int c = 0; c < NC; ++c) ss[tid][c] += ss[tid + off][c];
        }
        __syncthreads();
    }
    if (tid == 0) {
#pragma unroll
        for (int c = 0; c < NC; ++c) part[(size_t)blockIdx.x * NC + c] = ss[0][c];
    }
}

// ---- K5f: fused merge + mask + scatter (ws path) --------------------------
// Each block: re-merge the 256x8 partials (16 KB, L2-hit), compute mask for
// its 64 rows, write mask tail, then scatter x into the 8 community planes.
__global__ __launch_bounds__(256) void k_scatter_fused(
    const f32x4* __restrict__ x4, const double* __restrict__ raw,
    const double* __restrict__ part, float* __restrict__ mask_out,
    f32x4* __restrict__ out4) {
    __shared__ double ss[256][NC];   // 16 KB
    __shared__ float mlds[64 * NC];  // 2 KB
    int tid = threadIdx.x;

    // merge partials -> fin in ss[0][*] (same tree as the fallback k_col_final)
#pragma unroll
    for (int c = 0; c < NC; ++c) ss[tid][c] = part[(size_t)tid * NC + c];
    __syncthreads();
    for (int off = 128; off > 0; off >>= 1) {
        if (tid < off) {
#pragma unroll
            for (int c = 0; c < NC; ++c) ss[tid][c] += ss[tid + off][c];
        }
        __syncthreads();
    }

    int r0 = blockIdx.x * 64;
    int nrows = NN - r0; if (nrows > 64) nrows = 64;

    // per-row mask (fp64): threads 0..nrows-1, one row each
    if (tid < nrows) {
        int n = r0 + tid;
        double phi[NC];
        double r = 0.0;
#pragma unroll
        for (int c = 0; c < NC; ++c) {
            phi[c] = exp(raw[(size_t)n * NC + c]) / ss[0][c];
            r += phi[c];
        }
        double f = 8.0 - r;   // global sum of rowsums == 8 exactly
        double w[NC];
        double wmax = -1e300;
#pragma unroll
        for (int c = 0; c < NC; ++c) { w[c] = phi[c] * f; wmax = fmax(wmax, w[c]); }
#pragma unroll
        for (int c = 0; c < NC; ++c) {
            float bitf = ((w[c] == wmax) || (w[c] >= 1.0)) ? 1.0f : 0.0f;
            mlds[tid * NC + c] = bitf;
            mask_out[(size_t)n * NC + c] = bitf;
        }
    }
    __syncthreads();

    // scatter: 64 rows held in 16 f32x4 registers, c-major contiguous streams
    int nvec = nrows * 64;
    size_t base = (size_t)r0 * 64;
    f32x4 v[16];
#pragma unroll
    for (int i = 0; i < 16; ++i) {
        int idx = i * 256 + tid;
        v[i] = (idx < nvec) ? x4[base + idx] : (f32x4)(0.f);
    }
    const f32x4 zz = (f32x4)(0.f);
#pragma unroll
    for (int c = 0; c < NC; ++c) {
        size_t cbase = (size_t)c * NN * 64 + base;
#pragma unroll
        for (int i = 0; i < 16; ++i) {
            int idx = i * 256 + tid;
            if (idx < nvec) {
                int lr = idx >> 6;                      // wave-uniform row
                bool bit = mlds[lr * NC + c] != 0.0f;   // LDS broadcast
                __builtin_nontemporal_store(bit ? v[i] : zz, &out4[cbase + idx]);
            }
        }
    }
}

// ================= fallback path (scratch inside d_out) ====================
__global__ __launch_bounds__(256) void k_col_final(const double* __restrict__ part,
                                                   double* __restrict__ fin) {
    __shared__ double ss[256][NC];
    int tid = threadIdx.x;
#pragma unroll
    for (int c = 0; c < NC; ++c) ss[tid][c] = part[(size_t)tid * NC + c];
    __syncthreads();
    for (int off = 128; off > 0; off >>= 1) {
        if (tid < off) {
#pragma unroll
            for (int c = 0; c < NC; ++c) ss[tid][c] += ss[tid + off][c];
        }
        __syncthreads();
    }
    if (tid == 0) {
#pragma unroll
        for (int c = 0; c < NC; ++c) fin[c] = ss[0][c];
    }
}

__global__ __launch_bounds__(256) void k_mask(const double* __restrict__ raw,
                                              const double* __restrict__ fin,
                                              float* __restrict__ mask_out) {
    int n = blockIdx.x * blockDim.x + threadIdx.x;
    if (n >= NN) return;
    double phi[NC];
    double r = 0.0;
#pragma unroll
    for (int c = 0; c < NC; ++c) {
        phi[c] = exp(raw[(size_t)n * NC + c]) / fin[c];
        r += phi[c];
    }
    double f = 8.0 - r;
    double w[NC];
    double wmax = -1e300;
#pragma unroll
    for (int c = 0; c < NC; ++c) { w[c] = phi[c] * f; wmax = fmax(wmax, w[c]); }
#pragma unroll
    for (int c = 0; c < NC; ++c) {
        bool bit = (w[c] == wmax) || (w[c] >= 1.0);
        mask_out[(size_t)n * NC + c] = bit ? 1.0f : 0.0f;
    }
}

__global__ __launch_bounds__(256) void k_scatter(const f32x4* __restrict__ x4,
                                                 const float* __restrict__ mask,
                                                 f32x4* __restrict__ out4) {
    __shared__ float mlds[64 * NC];
    int tid = threadIdx.x;
    int r0 = blockIdx.x * 64;
    int nrows = NN - r0; if (nrows > 64) nrows = 64;
    int nvec = nrows * 64;
    size_t base = (size_t)r0 * 64;
    for (int k = tid; k < nrows * NC; k += 256)
        mlds[k] = mask[(size_t)r0 * NC + k];
    f32x4 v[16];
#pragma unroll
    for (int i = 0; i < 16; ++i) {
        int idx = i * 256 + tid;
        v[i] = (idx < nvec) ? x4[base + idx] : (f32x4)(0.f);
    }
    __syncthreads();
    const f32x4 zz = (f32x4)(0.f);
#pragma unroll
    for (int c = 0; c < NC; ++c) {
        size_t cbase = (size_t)c * NN * 64 + base;
#pragma unroll
        for (int i = 0; i < 16; ++i) {
            int idx = i * 256 + tid;
            if (idx < nvec) {
                int lr = idx >> 6;
                bool bit = mlds[lr * NC + c] != 0.0f;
                __builtin_nontemporal_store(bit ? v[i] : zz, &out4[cbase + idx]);
            }
        }
    }
}

extern "C" void kernel_launch(void* const* d_in, const int* in_sizes, int n_in,
                              void* d_out, int out_size, void* d_ws, size_t ws_size,
                              hipStream_t stream) {
    const f32x4* x4 = (const f32x4*)d_in[0];
    const f32x4* z4 = (const f32x4*)d_in[1];
    float* out = (float*)d_out;
    float* mask_out = out + XPARTS_FLOATS;

    const size_t RAW_BYTES  = (size_t)NN * NC * sizeof(double);   // 6.4 MB
    const size_t PART_BYTES = 256 * NC * sizeof(double);          // 16 KB

    if (ws_size >= RAW_BYTES + PART_BYTES) {
        // 3-kernel path: scratch in d_ws, mask fused into scatter
        double* raw  = (double*)d_ws;
        double* part = (double*)((char*)d_ws + RAW_BYTES);
        k_phi_raw      <<<(NN * 64 + 255) / 256, 256, 0, stream>>>(z4, raw);
        k_col_partial  <<<256, 256, 0, stream>>>(raw, part);
        k_scatter_fused<<<(NN + 63) / 64, 256, 0, stream>>>(x4, raw, part,
                                                            mask_out, (f32x4*)out);
    } else {
        // 5-kernel fallback: scratch carved from x_parts region of d_out
        double* raw  = (double*)out;
        double* part = (double*)(out + 2000000);
        double* fin  = (double*)(out + 2200000);
        k_phi_raw    <<<(NN * 64 + 255) / 256, 256, 0, stream>>>(z4, raw);
        k_col_partial<<<256, 256, 0, stream>>>(raw, part);
        k_col_final  <<<1, 256, 0, stream>>>(part, fin);
        k_mask       <<<(NN + 255) / 256, 256, 0, stream>>>(raw, fin, mask_out);
        k_scatter    <<<(NN + 63) / 64, 256, 0, stream>>>(x4, mask_out, (f32x4*)out);
    }
}